// Round 1
// 438.904 us; speedup vs baseline: 1.0059x; 1.0059x over previous
//
#include <hip/hip_runtime.h>

#define NUM_CLASSES 19
#define IGNORE_INDEX (-1)
#define BATCH 8
#define HW (512 * 1024)            // pixels per image, 2^19
#define NPIX (BATCH * HW)          // 4,194,304
#define NGROUP (NPIX / 4)          // 1,048,576 float4 groups
#define NBINS (3 * NUM_CLASSES)    // 57: label | pred | intersect
#define BINS_PAD 64                // padded per-block output slot
#define GPT 4                      // float4-groups per thread
#define THREADS 256
#define HBLOCKS (NGROUP / (THREADS * GPT))   // 1024
#define PADC 258                   // ushort row length: conflict-free update AND reduce

// v2: conflict-free per-THREAD LDS histograms (no atomics at all).
//  - h[bin][tid] ushort columns: each thread owns its column -> plain RMW.
//    PADC=258 => word addr = bin*129 + tid/2; 129%32==1 so update phase is
//    (bin + tid/2)%32 (~2-way, free) and the reduce phase (lane=bin reading
//    its row) is (bin+i)%32 (<=2-way, free). Max count/column = GPT*4 = 16.
//  - All 19 plane float4s loaded into registers BEFORE the argmax chain so
//    the 19 loads issue back-to-back (full MLP), then the serial compare runs.
//  - GPT=4 -> 1024 blocks: 4x fewer per-block partials for the finish kernel.
__global__ __launch_bounds__(THREADS) void iou_hist_kernel(
    const float* __restrict__ pred,
    const int* __restrict__ label,
    unsigned int* __restrict__ bh)
{
    __shared__ unsigned short h[NBINS][PADC];
    const int tid = threadIdx.x;

    {   // zero LDS (NBINS*PADC ushorts = 7353 words)
        unsigned int* h32 = (unsigned int*)&h[0][0];
        for (int i = tid; i < (NBINS * PADC) / 2; i += THREADS) h32[i] = 0u;
    }
    __syncthreads();

    const int gbase = blockIdx.x * (THREADS * GPT);   // first float4-group of block
    const int pbase = gbase << 2;                     // first pixel (4096/block, divides HW)
    const int b   = pbase >> 19;                      // image index (no straddle)
    const int hw0 = pbase & (HW - 1);
    const float4* __restrict__ p4 =
        (const float4*)(pred + (size_t)b * (size_t)(NUM_CLASSES * HW) + hw0);
    const int4* __restrict__ lab4 = (const int4*)label + gbase;

#pragma unroll
    for (int i = 0; i < GPT; ++i) {
        const int off = i * THREADS + tid;

        // ---- load ALL planes first: 19 independent loads in flight ----
        float4 v[NUM_CLASSES];
#pragma unroll
        for (int c = 0; c < NUM_CLASSES; ++c)
            v[c] = p4[(size_t)c * (HW / 4) + off];
        const int4 lab = lab4[off];

        // ---- argmax chain (strict > keeps first max, matching jnp.argmax) ----
        float4 best = v[0];
        int bx = 0, by = 0, bz = 0, bw = 0;
#pragma unroll
        for (int c = 1; c < NUM_CLASSES; ++c) {
            if (v[c].x > best.x) { best.x = v[c].x; bx = c; }
            if (v[c].y > best.y) { best.y = v[c].y; by = c; }
            if (v[c].z > best.z) { best.z = v[c].z; bz = c; }
            if (v[c].w > best.w) { best.w = v[c].w; bw = c; }
        }

        // ---- private-column histogram updates: no atomics, no conflicts ----
        {
            const int l = lab.x;
            if (l != IGNORE_INDEX) {
                const int lc = min(max(l, 0), NUM_CLASSES - 1);
                h[lc][tid]++;
                h[NUM_CLASSES + bx][tid]++;
                if (bx == l) h[2 * NUM_CLASSES + lc][tid]++;
            }
        }
        {
            const int l = lab.y;
            if (l != IGNORE_INDEX) {
                const int lc = min(max(l, 0), NUM_CLASSES - 1);
                h[lc][tid]++;
                h[NUM_CLASSES + by][tid]++;
                if (by == l) h[2 * NUM_CLASSES + lc][tid]++;
            }
        }
        {
            const int l = lab.z;
            if (l != IGNORE_INDEX) {
                const int lc = min(max(l, 0), NUM_CLASSES - 1);
                h[lc][tid]++;
                h[NUM_CLASSES + bz][tid]++;
                if (bz == l) h[2 * NUM_CLASSES + lc][tid]++;
            }
        }
        {
            const int l = lab.w;
            if (l != IGNORE_INDEX) {
                const int lc = min(max(l, 0), NUM_CLASSES - 1);
                h[lc][tid]++;
                h[NUM_CLASSES + bw][tid]++;
                if (bw == l) h[2 * NUM_CLASSES + lc][tid]++;
            }
        }
    }

    __syncthreads();
    // per-block partials: all 64 slots written unconditionally (d_ws poisoned).
    // Row sum as u32 words (129/row incl. zeroed pad); bank = (bin+i)%32 -> free.
    if (tid < BINS_PAD) {
        unsigned int s = 0u;
        if (tid < NBINS) {
            const unsigned int* row = (const unsigned int*)&h[tid][0];
#pragma unroll 8
            for (int i = 0; i < PADC / 2; ++i) {
                const unsigned int u = row[i];
                s += (u & 0xffffu) + (u >> 16);
            }
        }
        bh[(size_t)blockIdx.x * BINS_PAD + tid] = s;
    }
}

// Single-block reduce of HBLOCKS x BINS_PAD partials (now 256 KB, was 1 MB)
// + final scalar. 1 - nanmean(inter/union); union==0 -> skipped; all-NaN -> 0.5.
__global__ __launch_bounds__(1024) void iou_finish_kernel(
    const unsigned int* __restrict__ bh, float* __restrict__ out)
{
    __shared__ unsigned int part[16][BINS_PAD];
    const int tid = threadIdx.x;
    const int bin = tid & 63;
    const int row = tid >> 6;   // 0..15

    unsigned int s = 0;
    for (int b = row; b < HBLOCKS; b += 16)
        s += bh[(size_t)b * BINS_PAD + bin];   // coalesced across tid
    part[row][bin] = s;
    __syncthreads();

    if (tid < BINS_PAD) {
        unsigned int t = 0;
#pragma unroll
        for (int r = 0; r < 16; ++r) t += part[r][tid];
        part[0][tid] = t;
    }
    __syncthreads();

    if (tid == 0) {
        float sum = 0.0f;
        int cnt = 0;
        for (int c = 0; c < NUM_CLASSES; ++c) {
            const float a_lab = (float)part[0][c];
            const float a_prd = (float)part[0][NUM_CLASSES + c];
            const float a_int = (float)part[0][2 * NUM_CLASSES + c];
            const float a_uni = a_prd + a_lab - a_int;
            if (a_uni > 0.0f) { sum += a_int / a_uni; ++cnt; }
        }
        const float mean = (cnt > 0) ? (sum / (float)cnt) : 0.5f;
        out[0] = 1.0f - mean;
    }
}

extern "C" void kernel_launch(void* const* d_in, const int* in_sizes, int n_in,
                              void* d_out, int out_size, void* d_ws, size_t ws_size,
                              hipStream_t stream)
{
    const float* pred  = (const float*)d_in[0];
    const int*   label = (const int*)d_in[1];
    float*       out   = (float*)d_out;
    unsigned int* bh   = (unsigned int*)d_ws;   // HBLOCKS * BINS_PAD uints (256 KB)

    iou_hist_kernel<<<HBLOCKS, THREADS, 0, stream>>>(pred, label, bh);
    iou_finish_kernel<<<1, 1024, 0, stream>>>(bh, out);
}